// Round 19
// baseline (1057.139 us; speedup 1.0000x reference)
//
#include <hip/hip_runtime.h>

// ---------- types / helpers ----------
typedef __attribute__((ext_vector_type(8))) _Float16 f16x8;
typedef __attribute__((ext_vector_type(2))) _Float16 f16x2;
typedef __attribute__((ext_vector_type(4))) float floatx4;

union HFrag { uint4 u4; f16x8 v; unsigned short s[8]; };
union HS { _Float16 h; unsigned short u; };
union UH2 { unsigned int u; f16x2 h; };

__device__ __forceinline__ float bf2f(unsigned short u) {
  return __uint_as_float(((unsigned int)u) << 16);
}
__device__ __forceinline__ float h2f(unsigned short u) { HS z; z.u = u; return (float)z.h; }
__device__ __forceinline__ unsigned short f2h(float f) { HS z; z.h = (_Float16)f; return z.u; }
__device__ __forceinline__ float sigmf(float x) { return 1.0f / (1.0f + expf(-x)); }

// dtype-agnostic input load: f32 ? float : bf16
__device__ __forceinline__ float ldi(const void* p, long i, bool f32) {
  return f32 ? ((const float*)p)[i] : bf2f(((const unsigned short*)p)[i]);
}

// async global->LDS DMA, 16B per lane. LDS dest = wave-uniform base + lane*16.
__device__ __forceinline__ void dma16(unsigned short* lds, const unsigned short* g) {
  __builtin_amdgcn_global_load_lds(
      (const __attribute__((address_space(1))) unsigned int*)g,
      (__attribute__((address_space(3))) unsigned int*)lds,
      16, 0, 0);
}

// wave-local waits (gfx9 encoding: vm [3:0]|[15:14], exp [6:4], lgkm [11:8])
#define WAIT_VM0()   __builtin_amdgcn_s_waitcnt(0x0F70)
#define WAIT_LGKM0() __builtin_amdgcn_s_waitcnt(0xC07F)

// barrier that does NOT drain vmcnt (keeps DMA pipeline alive across it)
#define SAFE_BARRIER() do {                      \
  __builtin_amdgcn_sched_barrier(0);             \
  WAIT_LGKM0();                                  \
  __builtin_amdgcn_s_barrier();                  \
  __builtin_amdgcn_sched_barrier(0);             \
} while (0)

#define NNODES 32000
#define NEDGES 80000
#define NGRAPH 1000

#define MFMA_F16 __builtin_amdgcn_mfma_f32_16x16x32_f16

// ---------- dtype detect ----------
__global__ __launch_bounds__(256) void detect_kernel(
    const unsigned short* __restrict__ nf, int* __restrict__ flag) {
  __shared__ float sm[256];
  float m = 0.f;
  for (int i = threadIdx.x; i < 4096; i += 256) {
    float v = fabsf(bf2f(nf[i]));
    if (isfinite(v)) m = fmaxf(m, v);
    else m = 1e30f;
  }
  sm[threadIdx.x] = m;
  __syncthreads();
  if (threadIdx.x == 0) {
    float mm = 0.f;
    for (int i = 0; i < 256; ++i) mm = fmaxf(mm, sm[i]);
    flag[0] = (mm > 1e6f) ? 1 : 0;
  }
}

// ---------- prep: GRU weights -> fp16 [192][64] (j-major, transposed) ----------
__global__ __launch_bounds__(256) void prep_kernel(
    const int* __restrict__ dflag,
    const void* __restrict__ Wx, const void* __restrict__ Wh,
    const void* __restrict__ bx, const void* __restrict__ bh,
    const void* __restrict__ bconv,
    unsigned short* __restrict__ WxH, unsigned short* __restrict__ WhH,
    float* __restrict__ bxf, float* __restrict__ bhf, float* __restrict__ bconvf) {
  bool f32 = dflag[0] != 0;
  int idx = blockIdx.x * 256 + threadIdx.x;   // grid 48 -> 12288 = 192*64
  int j = idx >> 6, k = idx & 63;
  WxH[idx] = f2h(ldi(Wx, k * 192 + j, f32));
  WhH[idx] = f2h(ldi(Wh, k * 192 + j, f32));
  if (idx < 192) { bxf[idx] = ldi(bx, idx, f32); bhf[idx] = ldi(bh, idx, f32); }
  if (idx < 64) bconvf[idx] = ldi(bconv, idx, f32);
}

// ---------- prep: LSTM weights -> chunk-major float4 [chunk][gate] ----------
__global__ __launch_bounds__(256) void lstmprep_kernel(
    const int* __restrict__ dflag,
    const void* Wx0, const void* Wh0, const void* bx0, const void* bh0,
    const void* Wx1, const void* Wh1, const void* bx1, const void* bh1,
    const void* Wx2, const void* Wh2, const void* bx2, const void* bh2,
    float4* __restrict__ LW, float* __restrict__ bsum) {
  bool f32 = dflag[0] != 0;
  int idx = blockIdx.x * 256 + threadIdx.x;   // grid 112 -> 28672 float4
  int l, base, fi;
  if (idx < 12288)      { l = 0; base = 0;     fi = 128; }
  else if (idx < 20480) { l = 1; base = 12288; fi = 64; }
  else                  { l = 2; base = 20480; fi = 64; }
  const void* Wx = (l == 0) ? Wx0 : (l == 1) ? Wx1 : Wx2;
  const void* Wh = (l == 0) ? Wh0 : (l == 1) ? Wh1 : Wh2;
  int r = idx - base;
  int c = r >> 8, t = r & 255;
  float v[4];
#pragma unroll
  for (int i2 = 0; i2 < 4; ++i2) {
    int k = c * 4 + i2;
    v[i2] = (k < fi) ? ldi(Wx, (long)k * 256 + t, f32)
                     : ldi(Wh, (long)(k - fi) * 256 + t, f32);
  }
  float4 o; o.x = v[0]; o.y = v[1]; o.z = v[2]; o.w = v[3];
  LW[idx] = o;
  if (idx < 768) {
    int ll = idx >> 8, j = idx & 255;
    const void* bx = (ll == 0) ? bx0 : (ll == 1) ? bx1 : bx2;
    const void* bh = (ll == 0) ? bh0 : (ll == 1) ? bh1 : bh2;
    bsum[idx] = ldi(bx, j, f32) + ldi(bh, j, f32);
  }
}

// ---------- node projection: h = relu(nf @ Wp + bp) ----------
__global__ __launch_bounds__(256) void nodeproj_kernel(
    const int* __restrict__ dflag,
    const void* __restrict__ nf, const void* __restrict__ Wp,
    const void* __restrict__ bp, float* __restrict__ hstate) {
  bool f32 = dflag[0] != 0;
  int lane = threadIdx.x & 63;
  int n = blockIdx.x * 4 + (threadIdx.x >> 6);
  float acc = ldi(bp, lane, f32);
  for (int k = 0; k < 74; ++k)
    acc += ldi(nf, (long)n * 74 + k, f32) * ldi(Wp, k * 64 + lane, f32);
  hstate[n * 64 + lane] = fmaxf(acc, 0.0f);
}

// ---------- We2T: fp16 Bt tiles, per-k: [k 128][o 64][g' 8][j 8] ----------
// g' = g ^ (o&7), d = g*8 + j; value = We2[k][d*64 + o]
__global__ __launch_bounds__(256) void we2t_kernel(
    const int* __restrict__ dflag,
    const void* __restrict__ We2, unsigned short* __restrict__ We2T) {
  bool f32 = dflag[0] != 0;
  int idx = blockIdx.x * 256 + threadIdx.x;  // grid 2048 -> 524288
  int j = idx & 7;
  int gs = (idx >> 3) & 7;
  int o = (idx >> 6) & 63;
  int k = idx >> 12;                          // 0..127
  int g = gs ^ (o & 7);
  int d = g * 8 + j;
  We2T[idx] = f2h(ldi(We2, (long)k * 4096 + d * 64 + o, f32));
}

// ---------- be2T: fp16 Bt for hbe GEMM: [o 64][g' 8][j 8], g' = g^(o&7) ----
__global__ __launch_bounds__(256) void be2t_kernel(
    const int* __restrict__ dflag,
    const void* __restrict__ be2, unsigned short* __restrict__ be2T) {
  bool f32 = dflag[0] != 0;
  int idx = blockIdx.x * 256 + threadIdx.x;  // grid 16 -> 4096
  int j = idx & 7;
  int gs = (idx >> 3) & 7;
  int o = idx >> 6;
  int g = gs ^ (o & 7);
  int d = g * 8 + j;
  be2T[idx] = f2h(ldi(be2, (long)d * 64 + o, f32));
}

// ---------- CSR build (once per launch; dst is launch-invariant) ----------
__global__ __launch_bounds__(256) void count_kernel(
    const int* __restrict__ dst, int* __restrict__ cnt) {
  int e = blockIdx.x * 256 + threadIdx.x;
  if (e < NEDGES) atomicAdd(&cnt[dst[e]], 1);
}

__global__ __launch_bounds__(256) void scan_kernel(
    const int* __restrict__ cnt, int* __restrict__ row_ptr, int* __restrict__ cur) {
  __shared__ int part[256];
  int t = threadIdx.x;
  int base = t * 125;              // 256*125 = 32000
  int s = 0;
  for (int i = 0; i < 125; ++i) s += cnt[base + i];
  part[t] = s;
  __syncthreads();
  if (t == 0) {
    int run = 0;
    for (int i = 0; i < 256; ++i) { int v = part[i]; part[i] = run; run += v; }
  }
  __syncthreads();
  int run = part[t];
  for (int i = 0; i < 125; ++i) {
    row_ptr[base + i] = run;
    cur[base + i] = run;
    run += cnt[base + i];
  }
  if (t == 255) row_ptr[32000] = run;
}

__global__ __launch_bounds__(256) void fill_kernel(
    const int* __restrict__ dst, int* __restrict__ cur, int* __restrict__ eidx) {
  int e = blockIdx.x * 256 + threadIdx.x;
  if (e < NEDGES) { int p = atomicAdd(&cur[dst[e]], 1); eidx[p] = e; }
}

// ---------- uprep v2: ONE thread per edge computes all 128 u values ----------
__global__ __launch_bounds__(256) void uprep_kernel(
    const int* __restrict__ dflag,
    const void* __restrict__ ef, const void* __restrict__ We1,
    const void* __restrict__ be1, const int* __restrict__ eidx,
    unsigned int* __restrict__ uT) {
  bool f32 = dflag[0] != 0;
  __shared__ float we1_s[1536];
  __shared__ float be1_s[128];
  int t = threadIdx.x;
  for (int i = t; i < 1536; i += 256) we1_s[i] = ldi(We1, i, f32);
  if (t < 128) be1_s[t] = ldi(be1, t, f32);
  __syncthreads();
  int pos = blockIdx.x * 256 + t;
  if (pos >= NEDGES) return;
  int e = eidx[pos];
  float efr[12];
#pragma unroll
  for (int j = 0; j < 12; ++j) efr[j] = ldi(ef, (long)e * 12 + j, f32);
#pragma unroll 4
  for (int kp = 0; kp < 64; ++kp) {
    int k0 = kp * 2;
    float u0 = be1_s[k0], u1 = be1_s[k0 + 1];
#pragma unroll
    for (int j = 0; j < 12; ++j) {
      u0 += efr[j] * we1_s[j * 128 + k0];
      u1 += efr[j] * we1_s[j * 128 + k0 + 1];
    }
    u0 = fmaxf(u0, 0.f); u1 = fmaxf(u1, 0.f);
    HS a, b; a.h = (_Float16)u0; b.h = (_Float16)u1;
    uT[(size_t)kp * NEDGES + pos] = (unsigned int)a.u | ((unsigned int)b.u << 16);
  }
}

// ---------- fused MP step helpers ----------
__device__ __forceinline__ void issueB(unsigned short* L, const unsigned short* G,
                                       int w, int lane) {
  L += w * 1024; G += w * 1024 + lane * 8;
  dma16(L, G); dma16(L + 512, G + 512);
  dma16(L + 4096, G + 4096); dma16(L + 4096 + 512, G + 4096 + 512);
}

// ---------- fused MP step: Z-GEMM + edge pass + aggregate + GRU, in-place h ----
// Total-time-measured best (1056.6 / 1060.4 us): 51.7 KB LDS (single-buffer
// BtL, two-pass MS), __launch_bounds__(256,2) -> natural 128 VGPR (no spill),
// HW co-schedules ~2.5-3 blocks/CU (155 KB LDS, 384 VGPR <= limits).
__global__ __launch_bounds__(256, 2) void step_fused_kernel(
    const unsigned short* __restrict__ We2T,
    const unsigned short* __restrict__ be2T,
    const unsigned int* __restrict__ uT,
    const int* __restrict__ src, const int* __restrict__ eidx,
    const int* __restrict__ row_ptr,
    const unsigned short* __restrict__ WxH, const unsigned short* __restrict__ WhH,
    const float* __restrict__ bxf, const float* __restrict__ bhf,
    const float* __restrict__ bconvf,
    float* __restrict__ hstate) {
  __shared__ __align__(16) unsigned char RA[51712];
  unsigned short* BtL = (unsigned short*)RA;                             // 16384 B
  unsigned int (*Zs)[64][68] = (unsigned int (*)[64][68])(RA + 16384);   // 34816 B
  float (*MS)[64] = (float (*)[64])RA;                                   // 32768 B
  unsigned short (*Xhi)[72] = (unsigned short (*)[72])RA;                //  9216 B
  unsigned short (*Xlo)[72] = (unsigned short (*)[72])(RA + 9216);       //  9216 B
  unsigned short (*SRZ)[65] = (unsigned short (*)[65])(RA + 18432);      // 16640 B
  float (*NG)[65] = (float (*)[65])(RA + 35072);                         // 16640 B

  int t = threadIdx.x, lane = t & 63, w = t >> 6;
  int c16 = lane & 15, q = lane >> 4;
  int nb = blockIdx.x * 64;                              // 500 blocks
  int p0 = row_ptr[nb], p1 = row_ptr[nb + 64];
  int nE = p1 - p0;

  // ---- h fragments (B-operand, hi/lo fp16) straight from global ----
  HFrag bhi[4][2], blo[4][2];
#pragma unroll
  for (int nt = 0; nt < 4; ++nt)
#pragma unroll
    for (int ks = 0; ks < 2; ++ks) {
      const float* hp = hstate + (size_t)(nb + nt * 16 + c16) * 64 + ks * 32 + q * 8;
      float4 v0 = *(const float4*)hp;
      float4 v1 = *(const float4*)(hp + 4);
      float vv[8] = {v0.x, v0.y, v0.z, v0.w, v1.x, v1.y, v1.z, v1.w};
#pragma unroll
      for (int j = 0; j < 8; ++j) {
        HS hi; hi.h = (_Float16)vv[j];
        bhi[nt][ks].s[j] = hi.u;
        blo[nt][ks].s[j] = f2h(vv[j] - (float)hi.h);
      }
    }

  int arow = (w * 16 + c16) * 64;          // A-frag row base (shorts) per k-block
  int g0q = (q ^ (c16 & 7)) * 8;
  int g1q = ((4 + q) ^ (c16 & 7)) * 8;

  float aggv[16];
  {
    float bcv = bconvf[lane];
#pragma unroll
    for (int i = 0; i < 16; ++i) aggv[i] = bcv;
  }

  // ================= tile loop (phases 1+2) =================
  for (int et = 0; et < nE; et += 256) {
    int me = et + t;
    bool act = me < nE;
    int pos = p0 + (act ? me : 0);
    int r = src[eidx[pos]] - nb;             // 0..63 (in-graph edges)

    // ---- prologue: u0 + beT into BtL first half ----
    unsigned int ucur = uT[pos];             // k-pair 0
    dma16(BtL + w * 1024, be2T + w * 1024 + lane * 8);
    dma16(BtL + w * 1024 + 512, be2T + w * 1024 + 512 + lane * 8);
    WAIT_VM0();                              // u0 + beT ready

    // beT A-frags to regs, then B_0 may overwrite
    HFrag eb0, eb1;
    eb0.u4 = *(const uint4*)&BtL[arow + g0q];
    eb1.u4 = *(const uint4*)&BtL[arow + g1q];
    __builtin_amdgcn_sched_barrier(0);
    WAIT_LGKM0();
    __builtin_amdgcn_sched_barrier(0);
    issueB(BtL, We2T, w, lane);              // B_0 (chunk 0)

    // ---- hbe[o][n] = sum_d be2T[o][d] * h[n][d]  (f32) ----
    floatx4 hacc[4];
#pragma unroll
    for (int nt = 0; nt < 4; ++nt) hacc[nt] = (floatx4){0.f, 0.f, 0.f, 0.f};
#pragma unroll
    for (int nt = 0; nt < 4; ++nt) {
      hacc[nt] = MFMA_F16(eb0.v, bhi[nt][0].v, hacc[nt], 0, 0, 0);
      hacc[nt] = MFMA_F16(eb0.v, blo[nt][0].v, hacc[nt], 0, 0, 0);
      hacc[nt] = MFMA_F16(eb1.v, bhi[nt][1].v, hacc[nt], 0, 0, 0);
      hacc[nt] = MFMA_F16(eb1.v, blo[nt][1].v, hacc[nt], 0, 0, 0);
    }
    // store hbe (f32) -> Zs[1] as [n][o]
#pragma unroll
    for (int nt = 0; nt < 4; ++nt)
      *(floatx4*)&Zs[1][nt * 16 + c16][w * 16 + q * 4] = hacc[nt];
    SAFE_BARRIER();                          // Zs[1] (hbe) visible

    // ---- msg init from hbe ----
    floatx4 msgv[16];
    if (act) {
#pragma unroll
      for (int og = 0; og < 16; ++og)
        msgv[og] = *(const floatx4*)&Zs[1][r][og * 4];
    }

    // ---- chunk loop: 64 chunks x 2 k, single-buffered BtL ----
    for (int c = 0; c < 64; ++c) {
      WAIT_VM0();                            // chunk c's {u,B} group complete
      HFrag a00, a01, a10, a11;              // (k0|k1) x (d-half 0|1)
      a00.u4 = *(const uint4*)&BtL[arow + g0q];
      a01.u4 = *(const uint4*)&BtL[arow + g1q];
      a10.u4 = *(const uint4*)&BtL[4096 + arow + g0q];
      a11.u4 = *(const uint4*)&BtL[4096 + arow + g1q];
      __builtin_amdgcn_sched_barrier(0);
      WAIT_LGKM0();                          // frags in regs before overwrite
      __builtin_amdgcn_sched_barrier(0);
      unsigned int unext = 0;
      if (c + 1 < 64) {                      // issue {u_{c+1}, B_{c+1}}
        unext = uT[(size_t)(c + 1) * NEDGES + pos];
        issueB(BtL, We2T + (size_t)(c + 1) * 8192, w, lane);
      }
      floatx4 z0[4], z1[4];
#pragma unroll
      for (int nt = 0; nt < 4; ++nt) {
        z0[nt] = (floatx4){0.f, 0.f, 0.f, 0.f};
        z1[nt] = (floatx4){0.f, 0.f, 0.f, 0.f};
      }
#pragma unroll
      for (int nt = 0; nt < 4; ++nt) {
        z0[nt] = MFMA_F16(a00.v, bhi[nt][0].v, z0[nt], 0, 0, 0);
        z0[nt] = MFMA_F16(a00.v, blo[nt][0].v, z0[nt], 0, 0, 0);
        z0[nt] = MFMA_F16(a01.v, bhi[nt][1].v, z0[nt], 0, 0, 0);
        z0[nt] = MFMA_F16(a01.v, blo[nt][1].v, z0[nt], 0, 0, 0);
        z1[nt] = MFMA_F16(a10.v, bhi[nt][0].v, z1[nt], 0, 0, 0);
        z1[nt] = MFMA_F16(a10.v, blo[nt][0].v, z1[nt], 0, 0, 0);
        z1[nt] = MFMA_F16(a11.v, bhi[nt][1].v, z1[nt], 0, 0, 0);
        z1[nt] = MFMA_F16(a11.v, blo[nt][1].v, z1[nt], 0, 0, 0);
      }
      // pack (k0,k1) fp16 pairs and store to Zs[c&1]
      int zc = c & 1;
#pragma unroll
      for (int nt = 0; nt < 4; ++nt) {
        uint4 st;
        HS ph0, ph1;
        ph0.h = (_Float16)z0[nt][0]; ph1.h = (_Float16)z1[nt][0];
        st.x = (unsigned int)ph0.u | ((unsigned int)ph1.u << 16);
        ph0.h = (_Float16)z0[nt][1]; ph1.h = (_Float16)z1[nt][1];
        st.y = (unsigned int)ph0.u | ((unsigned int)ph1.u << 16);
        ph0.h = (_Float16)z0[nt][2]; ph1.h = (_Float16)z1[nt][2];
        st.z = (unsigned int)ph0.u | ((unsigned int)ph1.u << 16);
        ph0.h = (_Float16)z0[nt][3]; ph1.h = (_Float16)z1[nt][3];
        st.w = (unsigned int)ph0.u | ((unsigned int)ph1.u << 16);
        *(uint4*)&Zs[zc][nt * 16 + c16][w * 16 + q * 4] = st;
      }
      SAFE_BARRIER();                        // Z(c) visible; prev buf readers done

      // edge pass: u pair (fp16) . Z pairs via v_dot2_f32_f16
      if (act) {
        UH2 uu; uu.u = ucur;
#pragma unroll
        for (int og = 0; og < 16; ++og) {
          uint4 zz = *(const uint4*)&Zs[zc][r][og * 4];
          UH2 a;
          a.u = zz.x; msgv[og][0] = __builtin_amdgcn_fdot2(a.h, uu.h, msgv[og][0], false);
          a.u = zz.y; msgv[og][1] = __builtin_amdgcn_fdot2(a.h, uu.h, msgv[og][1], false);
          a.u = zz.z; msgv[og][2] = __builtin_amdgcn_fdot2(a.h, uu.h, msgv[og][2], false);
          a.u = zz.w; msgv[og][3] = __builtin_amdgcn_fdot2(a.h, uu.h, msgv[og][3], false);
        }
      }
      ucur = unext;
    }

    // ---- phase 2: msgv -> MS in two 128-edge passes, gather into aggv ----
    __syncthreads();                         // all Zs readers done; vmcnt == 0
    int nT = nE - et; if (nT > 256) nT = 256;
    int cgi = t & 63;
    int cq = cgi >> 2, cj = cgi & 3;
    // pass A: edges 0..127
    if (act && t < 128) {
      int t7 = t & 7;
#pragma unroll
      for (int og = 0; og < 16; ++og)
        *(floatx4*)&MS[t][(og ^ t7) * 4] = msgv[og];
    }
    __syncthreads();
    {
      int nA = nT < 128 ? nT : 128;
#pragma unroll
      for (int i = 0; i < 16; ++i) {
        int node = nb + (t >> 6) + i * 4;
        int rs = row_ptr[node] - p0 - et;
        int re = row_ptr[node + 1] - p0 - et;
        int lo = rs < 0 ? 0 : rs;
        int hi = re > nA ? nA : re;
        float a = aggv[i];
        for (int p = lo; p < hi; ++p)
          a += MS[p][((cq ^ (p & 7)) << 2) | cj];
        aggv[i] = a;
      }
    }
    __syncthreads();
    // pass B: edges 128..255
    if (act && t >= 128) {
      int t7 = t & 7;                        // (t-128)&7 == t&7
#pragma unroll
      for (int og = 0; og < 16; ++og)
        *(floatx4*)&MS[t - 128][(og ^ t7) * 4] = msgv[og];
    }
    __syncthreads();
    {
#pragma unroll
      for (int i = 0; i < 16; ++i) {
        int node = nb + (t >> 6) + i * 4;
        int rs = row_ptr[node] - p0 - et;
        int re = row_ptr[node + 1] - p0 - et;
        int lo = rs < 128 ? 128 : rs;
        int hi = re > nT ? nT : re;
        float a = aggv[i];
        for (int p = lo; p < hi; ++p)
          a += MS[p - 128][((cq ^ (p & 7)) << 2) | cj];
        aggv[i] = a;
      }
    }
    __syncthreads();                         // MS reads done before region reuse
  }

  // ================= phase 3: GRU (aliases region A) =================
  // X staging (hi/lo fp16)
#pragma unroll
  for (int i = 0; i < 16; ++i) {
    int n = (t >> 6) + i * 4;
    int c = t & 63;
    float x = fmaxf(aggv[i], 0.f);
    HS hx; hx.h = (_Float16)x;
    Xhi[n][c] = hx.u;
    Xlo[n][c] = f2h(x - (float)hx.h);
  }
  __syncthreads();

  floatx4 gx[3][4], gh[3][4];
#pragma unroll
  for (int jt = 0; jt < 3; ++jt)
#pragma unroll
    for (int nt = 0; nt < 4; ++nt) {
      gx[jt][nt] = (floatx4){0.f, 0.f, 0.f, 0.f};
      gh[jt][nt] = (floatx4){0.f, 0.f, 0.f, 0.f};
    }
#pragma unroll
  for (int kc = 0; kc < 2; ++kc) {
    int kof = kc * 32 + q * 8;
    HFrag ax[3], ah[3];
#pragma unroll
    for (int jt = 0; jt < 3; ++jt) {
      long off = (long)((w * 3 + jt) * 16 + c16) * 64 + kof;
      ax[jt].u4 = *(const uint4*)(WxH + off);
      ah[jt].u4 = *(const uint4*)(WhH + off);
    }
    HFrag bxh[4], bxl[4];
#pragma unroll
    for (int nt = 0; nt < 4; ++nt) {
      int n = nt * 16 + c16;
      bxh[nt].u4 = *(const uint4*)&Xhi[n][kof];
      bxl[nt].u4 = *(const uint4*)&Xlo[n][kof];
    }
#pragma unroll
    for (int jt = 0; jt < 3; ++jt)
#pragma unroll
      for (int nt = 0; nt < 4; ++nt) {
        gx[jt][nt] = MFMA_F16(ax[jt].v, bxh[nt].v, gx[jt][nt], 0, 0, 0);
        gx[jt][nt] = MFMA_F16(ax[jt].v, bxl[nt].v, gx[jt][nt], 0, 0, 0);
        gh[jt][nt] = MFMA_F16(ah[jt].v, bhi[nt][kc].v, gh[jt][nt], 0, 0, 0);
      }
  }

  // r,z -> SRZ (fp16); n-gate pre-activations kept in gx/gh registers
#pragma unroll
  for (int jt = 0; jt < 3; ++jt) {
#pragma unroll
    for (int rr = 0; rr < 4; ++rr) {
      int j = (w * 3 + jt) * 16 + q * 4 + rr;
      float bxv = bxf[j], bhv = bhf[j];
#pragma unroll
      for (int nt = 0; nt < 4; ++nt) {
        float vx = gx[jt][nt][rr] + bxv;
        float vh = gh[jt][nt][rr] + bhv;
        if (j < 128) {
          SRZ[j][nt * 16 + c16] = f2h(sigmf(vx + vh));
        } else {
          gx[jt][nt][rr] = vx;
          gh[jt][nt][rr] = vh;
        }
      }
    }
  }
  __syncthreads();                           // SRZ complete

  // n-gate: ng = tanh(gxn + r*ghn) -> NG (f32)
#pragma unroll
  for (int jt = 0; jt < 3; ++jt) {
#pragma unroll
    for (int rr = 0; rr < 4; ++rr) {
      int j = (w * 3 + jt) * 16 + q * 4 + rr;
      if (j >= 128) {
        int f = j - 128;
#pragma unroll
        for (int nt = 0; nt < 4; ++nt) {
          int n = nt * 16 + c16;
          float rg = h2f(SRZ[f][n]);
          NG[f][n] = tanhf(gx[jt][nt][rr] + rg * gh[jt][nt][rr]);
        }
      }
    }
  }
  __syncthreads();

  // final update (in-place hstate)
#pragma unroll
  for (int i = 0; i < 16; ++i) {
    int n = (t >> 6) + i * 4;
    int f = t & 63;
    float z = h2f(SRZ[64 + f][n]);
    float ng = NG[f][n];
    size_t gi = (size_t)(nb + n) * 64 + f;
    float ho = hstate[gi];
    hstate[gi] = (1.0f - z) * ng + z * ho;
  }
}

// ---------- Set2Set fused x6 + head: 2 graphs/block, 500 blocks ----------
__global__ __launch_bounds__(512) void s2s6_kernel(
    const int* __restrict__ dflag,
    const float* __restrict__ hstate,
    const float4* __restrict__ LW,        // [l0:48|l1:32|l2:32] x 256 float4
    const float* __restrict__ lstm_bsum,  // [3][256] bx+bh
    const void* __restrict__ Wout1, const void* __restrict__ bout1,
    const void* __restrict__ Wout2, const void* __restrict__ bout2,
    float* __restrict__ out) {
  bool f32 = dflag[0] != 0;
  __shared__ float xq[2][128];        // q_star per graph
  __shared__ float inb[2][192];       // combined [xq(fi) | h(64)] per graph
  __shared__ float gates[2][256];
  __shared__ float al[2][32];
  __shared__ float hsvf[384];         // 3 layers x 2 graphs x 64
  __shared__ float csvf[384];
  int g0 = blockIdx.x * 2;            // 500 blocks
  int t = threadIdx.x;

  for (int i = t; i < 256; i += 512) xq[i >> 7][i & 127] = 0.f;
  for (int i = t; i < 384; i += 512) { hsvf[i] = 0.f; csvf[i] = 0.f; }
  __syncthreads();

  int tt = t & 255, gp = t >> 8;      // gate id, graph index (0..1)

  for (int s = 0; s < 6; ++s) {
#pragma unroll
    for (int l = 0; l < 3; ++l) {
      const int fi = (l == 0) ? 128 : 64;
      const int tot = fi + 64;
      for (int i = t; i < 2 * tot; i += 512) {
        int g = i / tot, k = i - g * tot;
        inb[g][k] = (k < fi) ? xq[g][k] : hsvf[l * 128 + g * 64 + (k - fi)];
      }
      __syncthreads();
      const int nch = tot >> 2;
      const float4* wrow = LW + ((l == 0) ? 0 : (l == 1) ? 12288 : 20480) + tt;
      float bs = lstm_bsum[l * 256 + tt];
      float a0 = bs;
#pragma unroll 8
      for (int cch = 0; cch < nch; ++cch) {
        float4 wv = wrow[(size_t)cch * 256];
        float4 x0 = *(const float4*)&inb[gp][cch * 4];
        a0 += wv.x * x0.x + wv.y * x0.y + wv.z * x0.z + wv.w * x0.w;
      }
      gates[gp][tt] = a0;
      __syncthreads();
      if (t < 128) {
        int gg = t >> 6, u = t & 63;
        float ig = sigmf(gates[gg][u]);
        float fg = sigmf(gates[gg][64 + u]);
        float gv = tanhf(gates[gg][128 + u]);
        float og = sigmf(gates[gg][192 + u]);
        int ci = l * 128 + t;
        float cc = fg * csvf[ci] + ig * gv;
        float hn = og * tanhf(cc);
        csvf[ci] = cc;
        hsvf[ci] = hn;
        xq[gg][u] = hn;
      }
      __syncthreads();
    }
    if (t < 128) {
      int gg = t >> 6, tl = t & 63;
      int g = g0 + gg;
      int n = tl & 31, half = tl >> 5;
      const float* hrow = hstate + (size_t)(g * 32 + n) * 64 + half * 32;
      const float* qp = &xq[gg][half * 32];
      float p = 0.f;
#pragma unroll
      for (int k = 0; k < 32; ++k) p += hrow[k] * qp[k];
      p += __shfl_xor(p, 32, 64);
      if (half == 0) {
        float m = p;
#pragma unroll
        for (int s2 = 1; s2 < 32; s2 <<= 1) m = fmaxf(m, __shfl_xor(m, s2, 32));
        float e = expf(p - m);
        float sum = e;
#pragma unroll
        for (int s2 = 1; s2 < 32; s2 <<= 1) sum += __shfl_xor(sum, s2, 32);
        al[gg][n] = e / sum;
      }
      float acc = 0.f;
#pragma unroll 8
      for (int nn = 0; nn < 32; ++nn)
        acc += al[gg][nn] * hstate[(size_t)(g * 32 + nn) * 64 + tl];
      xq[gg][64 + tl] = acc;
    }
    __syncthreads();
  }

  // ---- head ----
  if (t < 128) {
    int gg = t >> 6, tl = t & 63;
    int g = g0 + gg;
    float acc = ldi(bout1, tl, f32);
#pragma unroll 16
    for (int k = 0; k < 128; ++k) acc += xq[gg][k] * ldi(Wout1, k * 64 + tl, f32);
    acc = fmaxf(acc, 0.0f);
    float p = acc * ldi(Wout2, tl, f32);
#pragma unroll
    for (int m = 1; m < 64; m <<= 1) p += __shfl_xor(p, m, 64);
    if (tl == 0) out[g] = p + ldi(bout2, 0, f32);
    out[1000 + g * 128 + tl] = xq[gg][tl];
    out[1000 + g * 128 + 64 + tl] = xq[gg][64 + tl];
  }
}

// ---------- launch ----------
extern "C" void kernel_launch(void* const* d_in, const int* in_sizes, int n_in,
                              void* d_out, int out_size, void* d_ws, size_t ws_size,
                              hipStream_t stream) {
  (void)in_sizes; (void)n_in; (void)out_size; (void)ws_size;
  const void* node_feats = d_in[0];
  const void* edge_feats = d_in[1];
  const int* src = (const int*)d_in[2];
  const int* dst = (const int*)d_in[3];
  const void* Wp = d_in[5];
  const void* bp = d_in[6];
  const void* We1 = d_in[7];
  const void* be1 = d_in[8];
  const void* We2 = d_in[9];
  const void* be2 = d_in[10];
  const void* b_conv = d_in[11];
  const void* gWx = d_in[12];
  const void* gWh = d_in[13];
  const void* gbx = d_in[14];
  const void* gbh = d_in[15];
  const void* Wout1 = d_in[16];
  const void* bout1 = d_in[17];
  const void* Wout2 = d_in[18];
  const void* bout2 = d_in[19];

  // workspace layout (~31.9 MB; proven-mapped region >= 44.5 MB)
  int* dflag = (int*)d_ws;                                    // 64 ints reserved
  float* hstate = (float*)d_ws + 64;                          // 32000*64 f32
  unsigned int* uT = (unsigned int*)(hstate + NNODES * 64);   // 64*80000 u32
  unsigned short* We2T = (unsigned short*)(uT + (size_t)NEDGES * 64); // 524288 fp16
  unsigned short* WxH = We2T + 524288;                        // 12288 fp16
  unsigned short* WhH = WxH + 12288;                          // 12288 fp16
  float* bxf = (float*)(WhH + 12288);                         // 192
  float* bhf = bxf + 192;                                     // 192
  float* bconvf = bhf + 192;                                  // 64
  int* row_ptr = (int*)(bconvf + 64);                         // 32001
  int* cur = row_ptr + 32001;                                 // 32000
  int* cnt = cur + 32000;                                     // 32000
  int* eidx = cnt + 32000;                                    // 80000
  uintptr_t lwp = (uintptr_t)(eidx + 80000);
  lwp = (lwp + 15) & ~(uintptr_t)15;                          // 16B align
  float4* LWf = (float4*)lwp;                                 // 28672 float4 (448 KB)
  float* lstm_bsum = (float*)(LWf + 28672);                   // 768 f32
  unsigned short* be2T = (unsigned short*)(lstm_bsum + 768);  // 4096 fp16

  (void)hipMemsetAsync(cnt, 0, (size_t)NNODES * sizeof(int), stream);

  detect_kernel<<<1, 256, 0, stream>>>((const unsigned short*)node_feats, dflag);
  prep_kernel<<<48, 256, 0, stream>>>(dflag, gWx, gWh, gbx, gbh, b_conv,
                                      WxH, WhH, bxf, bhf, bconvf);
  nodeproj_kernel<<<NNODES / 4, 256, 0, stream>>>(dflag, node_feats, Wp, bp, hstate);
  we2t_kernel<<<2048, 256, 0, stream>>>(dflag, We2, We2T);
  be2t_kernel<<<16, 256, 0, stream>>>(dflag, be2, be2T);
  lstmprep_kernel<<<112, 256, 0, stream>>>(dflag,
      d_in[20], d_in[21], d_in[22], d_in[23],
      d_in[24], d_in[25], d_in[26], d_in[27],
      d_in[28], d_in[29], d_in[30], d_in[31],
      LWf, lstm_bsum);

  count_kernel<<<(NEDGES + 255) / 256, 256, 0, stream>>>(dst, cnt);
  scan_kernel<<<1, 256, 0, stream>>>(cnt, row_ptr, cur);
  fill_kernel<<<(NEDGES + 255) / 256, 256, 0, stream>>>(dst, cur, eidx);
  uprep_kernel<<<(NEDGES + 255) / 256, 256, 0, stream>>>(
      dflag, edge_feats, We1, be1, eidx, uT);

  for (int step = 0; step < 6; ++step) {
    step_fused_kernel<<<NNODES / 64, 256, 0, stream>>>(
        We2T, be2T, uT, src, eidx, row_ptr, WxH, WhH, bxf, bhf, bconvf, hstate);
  }
  s2s6_kernel<<<NGRAPH / 2, 512, 0, stream>>>(dflag, hstate,
      (const float4*)LWf, lstm_bsum,
      Wout1, bout1, Wout2, bout2, (float*)d_out);
}

// Round 20
// 1054.278 us; speedup vs baseline: 1.0027x; 1.0027x over previous
//
#include <hip/hip_runtime.h>

// ---------- types / helpers ----------
typedef __attribute__((ext_vector_type(8))) _Float16 f16x8;
typedef __attribute__((ext_vector_type(2))) _Float16 f16x2;
typedef __attribute__((ext_vector_type(4))) float floatx4;

union HFrag { uint4 u4; f16x8 v; unsigned short s[8]; };
union HS { _Float16 h; unsigned short u; };
union UH2 { unsigned int u; f16x2 h; };

__device__ __forceinline__ float bf2f(unsigned short u) {
  return __uint_as_float(((unsigned int)u) << 16);
}
__device__ __forceinline__ float h2f(unsigned short u) { HS z; z.u = u; return (float)z.h; }
__device__ __forceinline__ unsigned short f2h(float f) { HS z; z.h = (_Float16)f; return z.u; }
__device__ __forceinline__ float sigmf(float x) { return 1.0f / (1.0f + expf(-x)); }

// dtype-agnostic input load: f32 ? float : bf16
__device__ __forceinline__ float ldi(const void* p, long i, bool f32) {
  return f32 ? ((const float*)p)[i] : bf2f(((const unsigned short*)p)[i]);
}

// async global->LDS DMA, 16B per lane. LDS dest = wave-uniform base + lane*16.
__device__ __forceinline__ void dma16(unsigned short* lds, const unsigned short* g) {
  __builtin_amdgcn_global_load_lds(
      (const __attribute__((address_space(1))) unsigned int*)g,
      (__attribute__((address_space(3))) unsigned int*)lds,
      16, 0, 0);
}

// wave-local waits (gfx9 encoding: vm [3:0]|[15:14], exp [6:4], lgkm [11:8])
#define WAIT_VM0()   __builtin_amdgcn_s_waitcnt(0x0F70)
#define WAIT_LGKM0() __builtin_amdgcn_s_waitcnt(0xC07F)

// barrier that does NOT drain vmcnt (keeps DMA pipeline alive across it)
#define SAFE_BARRIER() do {                      \
  __builtin_amdgcn_sched_barrier(0);             \
  WAIT_LGKM0();                                  \
  __builtin_amdgcn_s_barrier();                  \
  __builtin_amdgcn_sched_barrier(0);             \
} while (0)

#define NNODES 32000
#define NEDGES 80000
#define NGRAPH 1000

#define MFMA_F16 __builtin_amdgcn_mfma_f32_16x16x32_f16

// ---------- dtype detect ----------
__global__ __launch_bounds__(256) void detect_kernel(
    const unsigned short* __restrict__ nf, int* __restrict__ flag) {
  __shared__ float sm[256];
  float m = 0.f;
  for (int i = threadIdx.x; i < 4096; i += 256) {
    float v = fabsf(bf2f(nf[i]));
    if (isfinite(v)) m = fmaxf(m, v);
    else m = 1e30f;
  }
  sm[threadIdx.x] = m;
  __syncthreads();
  if (threadIdx.x == 0) {
    float mm = 0.f;
    for (int i = 0; i < 256; ++i) mm = fmaxf(mm, sm[i]);
    flag[0] = (mm > 1e6f) ? 1 : 0;
  }
}

// ---------- prep: GRU weights -> fp16 [192][64] (j-major, transposed) ----------
__global__ __launch_bounds__(256) void prep_kernel(
    const int* __restrict__ dflag,
    const void* __restrict__ Wx, const void* __restrict__ Wh,
    const void* __restrict__ bx, const void* __restrict__ bh,
    const void* __restrict__ bconv,
    unsigned short* __restrict__ WxH, unsigned short* __restrict__ WhH,
    float* __restrict__ bxf, float* __restrict__ bhf, float* __restrict__ bconvf) {
  bool f32 = dflag[0] != 0;
  int idx = blockIdx.x * 256 + threadIdx.x;   // grid 48 -> 12288 = 192*64
  int j = idx >> 6, k = idx & 63;
  WxH[idx] = f2h(ldi(Wx, k * 192 + j, f32));
  WhH[idx] = f2h(ldi(Wh, k * 192 + j, f32));
  if (idx < 192) { bxf[idx] = ldi(bx, idx, f32); bhf[idx] = ldi(bh, idx, f32); }
  if (idx < 64) bconvf[idx] = ldi(bconv, idx, f32);
}

// ---------- prep: LSTM weights -> chunk-major float4 [chunk][gate] ----------
__global__ __launch_bounds__(256) void lstmprep_kernel(
    const int* __restrict__ dflag,
    const void* Wx0, const void* Wh0, const void* bx0, const void* bh0,
    const void* Wx1, const void* Wh1, const void* bx1, const void* bh1,
    const void* Wx2, const void* Wh2, const void* bx2, const void* bh2,
    float4* __restrict__ LW, float* __restrict__ bsum) {
  bool f32 = dflag[0] != 0;
  int idx = blockIdx.x * 256 + threadIdx.x;   // grid 112 -> 28672 float4
  int l, base, fi;
  if (idx < 12288)      { l = 0; base = 0;     fi = 128; }
  else if (idx < 20480) { l = 1; base = 12288; fi = 64; }
  else                  { l = 2; base = 20480; fi = 64; }
  const void* Wx = (l == 0) ? Wx0 : (l == 1) ? Wx1 : Wx2;
  const void* Wh = (l == 0) ? Wh0 : (l == 1) ? Wh1 : Wh2;
  int r = idx - base;
  int c = r >> 8, t = r & 255;
  float v[4];
#pragma unroll
  for (int i2 = 0; i2 < 4; ++i2) {
    int k = c * 4 + i2;
    v[i2] = (k < fi) ? ldi(Wx, (long)k * 256 + t, f32)
                     : ldi(Wh, (long)(k - fi) * 256 + t, f32);
  }
  float4 o; o.x = v[0]; o.y = v[1]; o.z = v[2]; o.w = v[3];
  LW[idx] = o;
  if (idx < 768) {
    int ll = idx >> 8, j = idx & 255;
    const void* bx = (ll == 0) ? bx0 : (ll == 1) ? bx1 : bx2;
    const void* bh = (ll == 0) ? bh0 : (ll == 1) ? bh1 : bh2;
    bsum[idx] = ldi(bx, j, f32) + ldi(bh, j, f32);
  }
}

// ---------- node projection: h = relu(nf @ Wp + bp) ----------
__global__ __launch_bounds__(256) void nodeproj_kernel(
    const int* __restrict__ dflag,
    const void* __restrict__ nf, const void* __restrict__ Wp,
    const void* __restrict__ bp, float* __restrict__ hstate) {
  bool f32 = dflag[0] != 0;
  int lane = threadIdx.x & 63;
  int n = blockIdx.x * 4 + (threadIdx.x >> 6);
  float acc = ldi(bp, lane, f32);
  for (int k = 0; k < 74; ++k)
    acc += ldi(nf, (long)n * 74 + k, f32) * ldi(Wp, k * 64 + lane, f32);
  hstate[n * 64 + lane] = fmaxf(acc, 0.0f);
}

// ---------- We2T: fp16 Bt tiles, per-k: [k 128][o 64][g' 8][j 8] ----------
// g' = g ^ (o&7), d = g*8 + j; value = We2[k][d*64 + o]
__global__ __launch_bounds__(256) void we2t_kernel(
    const int* __restrict__ dflag,
    const void* __restrict__ We2, unsigned short* __restrict__ We2T) {
  bool f32 = dflag[0] != 0;
  int idx = blockIdx.x * 256 + threadIdx.x;  // grid 2048 -> 524288
  int j = idx & 7;
  int gs = (idx >> 3) & 7;
  int o = (idx >> 6) & 63;
  int k = idx >> 12;                          // 0..127
  int g = gs ^ (o & 7);
  int d = g * 8 + j;
  We2T[idx] = f2h(ldi(We2, (long)k * 4096 + d * 64 + o, f32));
}

// ---------- be2T: fp16 Bt for hbe GEMM: [o 64][g' 8][j 8], g' = g^(o&7) ----
__global__ __launch_bounds__(256) void be2t_kernel(
    const int* __restrict__ dflag,
    const void* __restrict__ be2, unsigned short* __restrict__ be2T) {
  bool f32 = dflag[0] != 0;
  int idx = blockIdx.x * 256 + threadIdx.x;  // grid 16 -> 4096
  int j = idx & 7;
  int gs = (idx >> 3) & 7;
  int o = idx >> 6;
  int g = gs ^ (o & 7);
  int d = g * 8 + j;
  be2T[idx] = f2h(ldi(be2, (long)d * 64 + o, f32));
}

// ---------- CSR build (once per launch; dst is launch-invariant) ----------
__global__ __launch_bounds__(256) void count_kernel(
    const int* __restrict__ dst, int* __restrict__ cnt) {
  int e = blockIdx.x * 256 + threadIdx.x;
  if (e < NEDGES) atomicAdd(&cnt[dst[e]], 1);
}

__global__ __launch_bounds__(256) void scan_kernel(
    const int* __restrict__ cnt, int* __restrict__ row_ptr, int* __restrict__ cur) {
  __shared__ int part[256];
  int t = threadIdx.x;
  int base = t * 125;              // 256*125 = 32000
  int s = 0;
  for (int i = 0; i < 125; ++i) s += cnt[base + i];
  part[t] = s;
  __syncthreads();
  if (t == 0) {
    int run = 0;
    for (int i = 0; i < 256; ++i) { int v = part[i]; part[i] = run; run += v; }
  }
  __syncthreads();
  int run = part[t];
  for (int i = 0; i < 125; ++i) {
    row_ptr[base + i] = run;
    cur[base + i] = run;
    run += cnt[base + i];
  }
  if (t == 255) row_ptr[32000] = run;
}

__global__ __launch_bounds__(256) void fill_kernel(
    const int* __restrict__ dst, int* __restrict__ cur, int* __restrict__ eidx) {
  int e = blockIdx.x * 256 + threadIdx.x;
  if (e < NEDGES) { int p = atomicAdd(&cur[dst[e]], 1); eidx[p] = e; }
}

// ---------- uprep v2: ONE thread per edge computes all 128 u values ----------
__global__ __launch_bounds__(256) void uprep_kernel(
    const int* __restrict__ dflag,
    const void* __restrict__ ef, const void* __restrict__ We1,
    const void* __restrict__ be1, const int* __restrict__ eidx,
    unsigned int* __restrict__ uT) {
  bool f32 = dflag[0] != 0;
  __shared__ float we1_s[1536];
  __shared__ float be1_s[128];
  int t = threadIdx.x;
  for (int i = t; i < 1536; i += 256) we1_s[i] = ldi(We1, i, f32);
  if (t < 128) be1_s[t] = ldi(be1, t, f32);
  __syncthreads();
  int pos = blockIdx.x * 256 + t;
  if (pos >= NEDGES) return;
  int e = eidx[pos];
  float efr[12];
#pragma unroll
  for (int j = 0; j < 12; ++j) efr[j] = ldi(ef, (long)e * 12 + j, f32);
#pragma unroll 4
  for (int kp = 0; kp < 64; ++kp) {
    int k0 = kp * 2;
    float u0 = be1_s[k0], u1 = be1_s[k0 + 1];
#pragma unroll
    for (int j = 0; j < 12; ++j) {
      u0 += efr[j] * we1_s[j * 128 + k0];
      u1 += efr[j] * we1_s[j * 128 + k0 + 1];
    }
    u0 = fmaxf(u0, 0.f); u1 = fmaxf(u1, 0.f);
    HS a, b; a.h = (_Float16)u0; b.h = (_Float16)u1;
    uT[(size_t)kp * NEDGES + pos] = (unsigned int)a.u | ((unsigned int)b.u << 16);
  }
}

// ---------- fused MP step helpers ----------
__device__ __forceinline__ void issueB(unsigned short* L, const unsigned short* G,
                                       int w, int lane) {
  L += w * 1024; G += w * 1024 + lane * 8;
  dma16(L, G); dma16(L + 512, G + 512);
  dma16(L + 4096, G + 4096); dma16(L + 4096 + 512, G + 4096 + 512);
}

// ---------- fused MP step: Z-GEMM + edge pass + aggregate + GRU, in-place h ----
// Final: thrice-measured best (1056.6/1057.1/1060.4 us total). 51.7 KB LDS
// (single-buffer BtL, two-pass MS), natural 128 VGPR (no spill), ~2.5 blk/CU.
__global__ __launch_bounds__(256, 2) void step_fused_kernel(
    const unsigned short* __restrict__ We2T,
    const unsigned short* __restrict__ be2T,
    const unsigned int* __restrict__ uT,
    const int* __restrict__ src, const int* __restrict__ eidx,
    const int* __restrict__ row_ptr,
    const unsigned short* __restrict__ WxH, const unsigned short* __restrict__ WhH,
    const float* __restrict__ bxf, const float* __restrict__ bhf,
    const float* __restrict__ bconvf,
    float* __restrict__ hstate) {
  __shared__ __align__(16) unsigned char RA[51712];
  unsigned short* BtL = (unsigned short*)RA;                             // 16384 B
  unsigned int (*Zs)[64][68] = (unsigned int (*)[64][68])(RA + 16384);   // 34816 B
  float (*MS)[64] = (float (*)[64])RA;                                   // 32768 B
  unsigned short (*Xhi)[72] = (unsigned short (*)[72])RA;                //  9216 B
  unsigned short (*Xlo)[72] = (unsigned short (*)[72])(RA + 9216);       //  9216 B
  unsigned short (*SRZ)[65] = (unsigned short (*)[65])(RA + 18432);      // 16640 B
  float (*NG)[65] = (float (*)[65])(RA + 35072);                         // 16640 B

  int t = threadIdx.x, lane = t & 63, w = t >> 6;
  int c16 = lane & 15, q = lane >> 4;
  int nb = blockIdx.x * 64;                              // 500 blocks
  int p0 = row_ptr[nb], p1 = row_ptr[nb + 64];
  int nE = p1 - p0;

  // ---- h fragments (B-operand, hi/lo fp16) straight from global ----
  HFrag bhi[4][2], blo[4][2];
#pragma unroll
  for (int nt = 0; nt < 4; ++nt)
#pragma unroll
    for (int ks = 0; ks < 2; ++ks) {
      const float* hp = hstate + (size_t)(nb + nt * 16 + c16) * 64 + ks * 32 + q * 8;
      float4 v0 = *(const float4*)hp;
      float4 v1 = *(const float4*)(hp + 4);
      float vv[8] = {v0.x, v0.y, v0.z, v0.w, v1.x, v1.y, v1.z, v1.w};
#pragma unroll
      for (int j = 0; j < 8; ++j) {
        HS hi; hi.h = (_Float16)vv[j];
        bhi[nt][ks].s[j] = hi.u;
        blo[nt][ks].s[j] = f2h(vv[j] - (float)hi.h);
      }
    }

  int arow = (w * 16 + c16) * 64;          // A-frag row base (shorts) per k-block
  int g0q = (q ^ (c16 & 7)) * 8;
  int g1q = ((4 + q) ^ (c16 & 7)) * 8;

  float aggv[16];
  {
    float bcv = bconvf[lane];
#pragma unroll
    for (int i = 0; i < 16; ++i) aggv[i] = bcv;
  }

  // ================= tile loop (phases 1+2) =================
  for (int et = 0; et < nE; et += 256) {
    int me = et + t;
    bool act = me < nE;
    int pos = p0 + (act ? me : 0);
    int r = src[eidx[pos]] - nb;             // 0..63 (in-graph edges)

    // ---- prologue: u0 + beT into BtL first half ----
    unsigned int ucur = uT[pos];             // k-pair 0
    dma16(BtL + w * 1024, be2T + w * 1024 + lane * 8);
    dma16(BtL + w * 1024 + 512, be2T + w * 1024 + 512 + lane * 8);
    WAIT_VM0();                              // u0 + beT ready

    // beT A-frags to regs, then B_0 may overwrite
    HFrag eb0, eb1;
    eb0.u4 = *(const uint4*)&BtL[arow + g0q];
    eb1.u4 = *(const uint4*)&BtL[arow + g1q];
    __builtin_amdgcn_sched_barrier(0);
    WAIT_LGKM0();
    __builtin_amdgcn_sched_barrier(0);
    issueB(BtL, We2T, w, lane);              // B_0 (chunk 0)

    // ---- hbe[o][n] = sum_d be2T[o][d] * h[n][d]  (f32) ----
    floatx4 hacc[4];
#pragma unroll
    for (int nt = 0; nt < 4; ++nt) hacc[nt] = (floatx4){0.f, 0.f, 0.f, 0.f};
#pragma unroll
    for (int nt = 0; nt < 4; ++nt) {
      hacc[nt] = MFMA_F16(eb0.v, bhi[nt][0].v, hacc[nt], 0, 0, 0);
      hacc[nt] = MFMA_F16(eb0.v, blo[nt][0].v, hacc[nt], 0, 0, 0);
      hacc[nt] = MFMA_F16(eb1.v, bhi[nt][1].v, hacc[nt], 0, 0, 0);
      hacc[nt] = MFMA_F16(eb1.v, blo[nt][1].v, hacc[nt], 0, 0, 0);
    }
    // store hbe (f32) -> Zs[1] as [n][o]
#pragma unroll
    for (int nt = 0; nt < 4; ++nt)
      *(floatx4*)&Zs[1][nt * 16 + c16][w * 16 + q * 4] = hacc[nt];
    SAFE_BARRIER();                          // Zs[1] (hbe) visible

    // ---- msg init from hbe ----
    floatx4 msgv[16];
    if (act) {
#pragma unroll
      for (int og = 0; og < 16; ++og)
        msgv[og] = *(const floatx4*)&Zs[1][r][og * 4];
    }

    // ---- chunk loop: 64 chunks x 2 k, single-buffered BtL ----
    for (int c = 0; c < 64; ++c) {
      WAIT_VM0();                            // chunk c's {u,B} group complete
      HFrag a00, a01, a10, a11;              // (k0|k1) x (d-half 0|1)
      a00.u4 = *(const uint4*)&BtL[arow + g0q];
      a01.u4 = *(const uint4*)&BtL[arow + g1q];
      a10.u4 = *(const uint4*)&BtL[4096 + arow + g0q];
      a11.u4 = *(const uint4*)&BtL[4096 + arow + g1q];
      __builtin_amdgcn_sched_barrier(0);
      WAIT_LGKM0();                          // frags in regs before overwrite
      __builtin_amdgcn_sched_barrier(0);
      unsigned int unext = 0;
      if (c + 1 < 64) {                      // issue {u_{c+1}, B_{c+1}}
        unext = uT[(size_t)(c + 1) * NEDGES + pos];
        issueB(BtL, We2T + (size_t)(c + 1) * 8192, w, lane);
      }
      floatx4 z0[4], z1[4];
#pragma unroll
      for (int nt = 0; nt < 4; ++nt) {
        z0[nt] = (floatx4){0.f, 0.f, 0.f, 0.f};
        z1[nt] = (floatx4){0.f, 0.f, 0.f, 0.f};
      }
#pragma unroll
      for (int nt = 0; nt < 4; ++nt) {
        z0[nt] = MFMA_F16(a00.v, bhi[nt][0].v, z0[nt], 0, 0, 0);
        z0[nt] = MFMA_F16(a00.v, blo[nt][0].v, z0[nt], 0, 0, 0);
        z0[nt] = MFMA_F16(a01.v, bhi[nt][1].v, z0[nt], 0, 0, 0);
        z0[nt] = MFMA_F16(a01.v, blo[nt][1].v, z0[nt], 0, 0, 0);
        z1[nt] = MFMA_F16(a10.v, bhi[nt][0].v, z1[nt], 0, 0, 0);
        z1[nt] = MFMA_F16(a10.v, blo[nt][0].v, z1[nt], 0, 0, 0);
        z1[nt] = MFMA_F16(a11.v, bhi[nt][1].v, z1[nt], 0, 0, 0);
        z1[nt] = MFMA_F16(a11.v, blo[nt][1].v, z1[nt], 0, 0, 0);
      }
      // pack (k0,k1) fp16 pairs and store to Zs[c&1]
      int zc = c & 1;
#pragma unroll
      for (int nt = 0; nt < 4; ++nt) {
        uint4 st;
        HS ph0, ph1;
        ph0.h = (_Float16)z0[nt][0]; ph1.h = (_Float16)z1[nt][0];
        st.x = (unsigned int)ph0.u | ((unsigned int)ph1.u << 16);
        ph0.h = (_Float16)z0[nt][1]; ph1.h = (_Float16)z1[nt][1];
        st.y = (unsigned int)ph0.u | ((unsigned int)ph1.u << 16);
        ph0.h = (_Float16)z0[nt][2]; ph1.h = (_Float16)z1[nt][2];
        st.z = (unsigned int)ph0.u | ((unsigned int)ph1.u << 16);
        ph0.h = (_Float16)z0[nt][3]; ph1.h = (_Float16)z1[nt][3];
        st.w = (unsigned int)ph0.u | ((unsigned int)ph1.u << 16);
        *(uint4*)&Zs[zc][nt * 16 + c16][w * 16 + q * 4] = st;
      }
      SAFE_BARRIER();                        // Z(c) visible; prev buf readers done

      // edge pass: u pair (fp16) . Z pairs via v_dot2_f32_f16
      if (act) {
        UH2 uu; uu.u = ucur;
#pragma unroll
        for (int og = 0; og < 16; ++og) {
          uint4 zz = *(const uint4*)&Zs[zc][r][og * 4];
          UH2 a;
          a.u = zz.x; msgv[og][0] = __builtin_amdgcn_fdot2(a.h, uu.h, msgv[og][0], false);
          a.u = zz.y; msgv[og][1] = __builtin_amdgcn_fdot2(a.h, uu.h, msgv[og][1], false);
          a.u = zz.z; msgv[og][2] = __builtin_amdgcn_fdot2(a.h, uu.h, msgv[og][2], false);
          a.u = zz.w; msgv[og][3] = __builtin_amdgcn_fdot2(a.h, uu.h, msgv[og][3], false);
        }
      }
      ucur = unext;
    }

    // ---- phase 2: msgv -> MS in two 128-edge passes, gather into aggv ----
    __syncthreads();                         // all Zs readers done; vmcnt == 0
    int nT = nE - et; if (nT > 256) nT = 256;
    int cgi = t & 63;
    int cq = cgi >> 2, cj = cgi & 3;
    // pass A: edges 0..127
    if (act && t < 128) {
      int t7 = t & 7;
#pragma unroll
      for (int og = 0; og < 16; ++og)
        *(floatx4*)&MS[t][(og ^ t7) * 4] = msgv[og];
    }
    __syncthreads();
    {
      int nA = nT < 128 ? nT : 128;
#pragma unroll
      for (int i = 0; i < 16; ++i) {
        int node = nb + (t >> 6) + i * 4;
        int rs = row_ptr[node] - p0 - et;
        int re = row_ptr[node + 1] - p0 - et;
        int lo = rs < 0 ? 0 : rs;
        int hi = re > nA ? nA : re;
        float a = aggv[i];
        for (int p = lo; p < hi; ++p)
          a += MS[p][((cq ^ (p & 7)) << 2) | cj];
        aggv[i] = a;
      }
    }
    __syncthreads();
    // pass B: edges 128..255
    if (act && t >= 128) {
      int t7 = t & 7;                        // (t-128)&7 == t&7
#pragma unroll
      for (int og = 0; og < 16; ++og)
        *(floatx4*)&MS[t - 128][(og ^ t7) * 4] = msgv[og];
    }
    __syncthreads();
    {
#pragma unroll
      for (int i = 0; i < 16; ++i) {
        int node = nb + (t >> 6) + i * 4;
        int rs = row_ptr[node] - p0 - et;
        int re = row_ptr[node + 1] - p0 - et;
        int lo = rs < 128 ? 128 : rs;
        int hi = re > nT ? nT : re;
        float a = aggv[i];
        for (int p = lo; p < hi; ++p)
          a += MS[p - 128][((cq ^ (p & 7)) << 2) | cj];
        aggv[i] = a;
      }
    }
    __syncthreads();                         // MS reads done before region reuse
  }

  // ================= phase 3: GRU (aliases region A) =================
  // X staging (hi/lo fp16)
#pragma unroll
  for (int i = 0; i < 16; ++i) {
    int n = (t >> 6) + i * 4;
    int c = t & 63;
    float x = fmaxf(aggv[i], 0.f);
    HS hx; hx.h = (_Float16)x;
    Xhi[n][c] = hx.u;
    Xlo[n][c] = f2h(x - (float)hx.h);
  }
  __syncthreads();

  floatx4 gx[3][4], gh[3][4];
#pragma unroll
  for (int jt = 0; jt < 3; ++jt)
#pragma unroll
    for (int nt = 0; nt < 4; ++nt) {
      gx[jt][nt] = (floatx4){0.f, 0.f, 0.f, 0.f};
      gh[jt][nt] = (floatx4){0.f, 0.f, 0.f, 0.f};
    }
#pragma unroll
  for (int kc = 0; kc < 2; ++kc) {
    int kof = kc * 32 + q * 8;
    HFrag ax[3], ah[3];
#pragma unroll
    for (int jt = 0; jt < 3; ++jt) {
      long off = (long)((w * 3 + jt) * 16 + c16) * 64 + kof;
      ax[jt].u4 = *(const uint4*)(WxH + off);
      ah[jt].u4 = *(const uint4*)(WhH + off);
    }
    HFrag bxh[4], bxl[4];
#pragma unroll
    for (int nt = 0; nt < 4; ++nt) {
      int n = nt * 16 + c16;
      bxh[nt].u4 = *(const uint4*)&Xhi[n][kof];
      bxl[nt].u4 = *(const uint4*)&Xlo[n][kof];
    }
#pragma unroll
    for (int jt = 0; jt < 3; ++jt)
#pragma unroll
      for (int nt = 0; nt < 4; ++nt) {
        gx[jt][nt] = MFMA_F16(ax[jt].v, bxh[nt].v, gx[jt][nt], 0, 0, 0);
        gx[jt][nt] = MFMA_F16(ax[jt].v, bxl[nt].v, gx[jt][nt], 0, 0, 0);
        gh[jt][nt] = MFMA_F16(ah[jt].v, bhi[nt][kc].v, gh[jt][nt], 0, 0, 0);
      }
  }

  // r,z -> SRZ (fp16); n-gate pre-activations kept in gx/gh registers
#pragma unroll
  for (int jt = 0; jt < 3; ++jt) {
#pragma unroll
    for (int rr = 0; rr < 4; ++rr) {
      int j = (w * 3 + jt) * 16 + q * 4 + rr;
      float bxv = bxf[j], bhv = bhf[j];
#pragma unroll
      for (int nt = 0; nt < 4; ++nt) {
        float vx = gx[jt][nt][rr] + bxv;
        float vh = gh[jt][nt][rr] + bhv;
        if (j < 128) {
          SRZ[j][nt * 16 + c16] = f2h(sigmf(vx + vh));
        } else {
          gx[jt][nt][rr] = vx;
          gh[jt][nt][rr] = vh;
        }
      }
    }
  }
  __syncthreads();                           // SRZ complete

  // n-gate: ng = tanh(gxn + r*ghn) -> NG (f32)
#pragma unroll
  for (int jt = 0; jt < 3; ++jt) {
#pragma unroll
    for (int rr = 0; rr < 4; ++rr) {
      int j = (w * 3 + jt) * 16 + q * 4 + rr;
      if (j >= 128) {
        int f = j - 128;
#pragma unroll
        for (int nt = 0; nt < 4; ++nt) {
          int n = nt * 16 + c16;
          float rg = h2f(SRZ[f][n]);
          NG[f][n] = tanhf(gx[jt][nt][rr] + rg * gh[jt][nt][rr]);
        }
      }
    }
  }
  __syncthreads();

  // final update (in-place hstate)
#pragma unroll
  for (int i = 0; i < 16; ++i) {
    int n = (t >> 6) + i * 4;
    int f = t & 63;
    float z = h2f(SRZ[64 + f][n]);
    float ng = NG[f][n];
    size_t gi = (size_t)(nb + n) * 64 + f;
    float ho = hstate[gi];
    hstate[gi] = (1.0f - z) * ng + z * ho;
  }
}

// ---------- Set2Set fused x6 + head: 2 graphs/block, 500 blocks ----------
__global__ __launch_bounds__(512) void s2s6_kernel(
    const int* __restrict__ dflag,
    const float* __restrict__ hstate,
    const float4* __restrict__ LW,        // [l0:48|l1:32|l2:32] x 256 float4
    const float* __restrict__ lstm_bsum,  // [3][256] bx+bh
    const void* __restrict__ Wout1, const void* __restrict__ bout1,
    const void* __restrict__ Wout2, const void* __restrict__ bout2,
    float* __restrict__ out) {
  bool f32 = dflag[0] != 0;
  __shared__ float xq[2][128];        // q_star per graph
  __shared__ float inb[2][192];       // combined [xq(fi) | h(64)] per graph
  __shared__ float gates[2][256];
  __shared__ float al[2][32];
  __shared__ float hsvf[384];         // 3 layers x 2 graphs x 64
  __shared__ float csvf[384];
  int g0 = blockIdx.x * 2;            // 500 blocks
  int t = threadIdx.x;

  for (int i = t; i < 256; i += 512) xq[i >> 7][i & 127] = 0.f;
  for (int i = t; i < 384; i += 512) { hsvf[i] = 0.f; csvf[i] = 0.f; }
  __syncthreads();

  int tt = t & 255, gp = t >> 8;      // gate id, graph index (0..1)

  for (int s = 0; s < 6; ++s) {
#pragma unroll
    for (int l = 0; l < 3; ++l) {
      const int fi = (l == 0) ? 128 : 64;
      const int tot = fi + 64;
      for (int i = t; i < 2 * tot; i += 512) {
        int g = i / tot, k = i - g * tot;
        inb[g][k] = (k < fi) ? xq[g][k] : hsvf[l * 128 + g * 64 + (k - fi)];
      }
      __syncthreads();
      const int nch = tot >> 2;
      const float4* wrow = LW + ((l == 0) ? 0 : (l == 1) ? 12288 : 20480) + tt;
      float bs = lstm_bsum[l * 256 + tt];
      float a0 = bs;
#pragma unroll 8
      for (int cch = 0; cch < nch; ++cch) {
        float4 wv = wrow[(size_t)cch * 256];
        float4 x0 = *(const float4*)&inb[gp][cch * 4];
        a0 += wv.x * x0.x + wv.y * x0.y + wv.z * x0.z + wv.w * x0.w;
      }
      gates[gp][tt] = a0;
      __syncthreads();
      if (t < 128) {
        int gg = t >> 6, u = t & 63;
        float ig = sigmf(gates[gg][u]);
        float fg = sigmf(gates[gg][64 + u]);
        float gv = tanhf(gates[gg][128 + u]);
        float og = sigmf(gates[gg][192 + u]);
        int ci = l * 128 + t;
        float cc = fg * csvf[ci] + ig * gv;
        float hn = og * tanhf(cc);
        csvf[ci] = cc;
        hsvf[ci] = hn;
        xq[gg][u] = hn;
      }
      __syncthreads();
    }
    if (t < 128) {
      int gg = t >> 6, tl = t & 63;
      int g = g0 + gg;
      int n = tl & 31, half = tl >> 5;
      const float* hrow = hstate + (size_t)(g * 32 + n) * 64 + half * 32;
      const float* qp = &xq[gg][half * 32];
      float p = 0.f;
#pragma unroll
      for (int k = 0; k < 32; ++k) p += hrow[k] * qp[k];
      p += __shfl_xor(p, 32, 64);
      if (half == 0) {
        float m = p;
#pragma unroll
        for (int s2 = 1; s2 < 32; s2 <<= 1) m = fmaxf(m, __shfl_xor(m, s2, 32));
        float e = expf(p - m);
        float sum = e;
#pragma unroll
        for (int s2 = 1; s2 < 32; s2 <<= 1) sum += __shfl_xor(sum, s2, 32);
        al[gg][n] = e / sum;
      }
      float acc = 0.f;
#pragma unroll 8
      for (int nn = 0; nn < 32; ++nn)
        acc += al[gg][nn] * hstate[(size_t)(g * 32 + nn) * 64 + tl];
      xq[gg][64 + tl] = acc;
    }
    __syncthreads();
  }

  // ---- head ----
  if (t < 128) {
    int gg = t >> 6, tl = t & 63;
    int g = g0 + gg;
    float acc = ldi(bout1, tl, f32);
#pragma unroll 16
    for (int k = 0; k < 128; ++k) acc += xq[gg][k] * ldi(Wout1, k * 64 + tl, f32);
    acc = fmaxf(acc, 0.0f);
    float p = acc * ldi(Wout2, tl, f32);
#pragma unroll
    for (int m = 1; m < 64; m <<= 1) p += __shfl_xor(p, m, 64);
    if (tl == 0) out[g] = p + ldi(bout2, 0, f32);
    out[1000 + g * 128 + tl] = xq[gg][tl];
    out[1000 + g * 128 + 64 + tl] = xq[gg][64 + tl];
  }
}

// ---------- launch ----------
extern "C" void kernel_launch(void* const* d_in, const int* in_sizes, int n_in,
                              void* d_out, int out_size, void* d_ws, size_t ws_size,
                              hipStream_t stream) {
  (void)in_sizes; (void)n_in; (void)out_size; (void)ws_size;
  const void* node_feats = d_in[0];
  const void* edge_feats = d_in[1];
  const int* src = (const int*)d_in[2];
  const int* dst = (const int*)d_in[3];
  const void* Wp = d_in[5];
  const void* bp = d_in[6];
  const void* We1 = d_in[7];
  const void* be1 = d_in[8];
  const void* We2 = d_in[9];
  const void* be2 = d_in[10];
  const void* b_conv = d_in[11];
  const void* gWx = d_in[12];
  const void* gWh = d_in[13];
  const void* gbx = d_in[14];
  const void* gbh = d_in[15];
  const void* Wout1 = d_in[16];
  const void* bout1 = d_in[17];
  const void* Wout2 = d_in[18];
  const void* bout2 = d_in[19];

  // workspace layout (~31.9 MB; proven-mapped region >= 44.5 MB)
  int* dflag = (int*)d_ws;                                    // 64 ints reserved
  float* hstate = (float*)d_ws + 64;                          // 32000*64 f32
  unsigned int* uT = (unsigned int*)(hstate + NNODES * 64);   // 64*80000 u32
  unsigned short* We2T = (unsigned short*)(uT + (size_t)NEDGES * 64); // 524288 fp16
  unsigned short* WxH = We2T + 524288;                        // 12288 fp16
  unsigned short* WhH = WxH + 12288;                          // 12288 fp16
  float* bxf = (float*)(WhH + 12288);                         // 192
  float* bhf = bxf + 192;                                     // 192
  float* bconvf = bhf + 192;                                  // 64
  int* row_ptr = (int*)(bconvf + 64);                         // 32001
  int* cur = row_ptr + 32001;                                 // 32000
  int* cnt = cur + 32000;                                     // 32000
  int* eidx = cnt + 32000;                                    // 80000
  uintptr_t lwp = (uintptr_t)(eidx + 80000);
  lwp = (lwp + 15) & ~(uintptr_t)15;                          // 16B align
  float4* LWf = (float4*)lwp;                                 // 28672 float4 (448 KB)
  float* lstm_bsum = (float*)(LWf + 28672);                   // 768 f32
  unsigned short* be2T = (unsigned short*)(lstm_bsum + 768);  // 4096 fp16

  (void)hipMemsetAsync(cnt, 0, (size_t)NNODES * sizeof(int), stream);

  detect_kernel<<<1, 256, 0, stream>>>((const unsigned short*)node_feats, dflag);
  prep_kernel<<<48, 256, 0, stream>>>(dflag, gWx, gWh, gbx, gbh, b_conv,
                                      WxH, WhH, bxf, bhf, bconvf);
  nodeproj_kernel<<<NNODES / 4, 256, 0, stream>>>(dflag, node_feats, Wp, bp, hstate);
  we2t_kernel<<<2048, 256, 0, stream>>>(dflag, We2, We2T);
  be2t_kernel<<<16, 256, 0, stream>>>(dflag, be2, be2T);
  lstmprep_kernel<<<112, 256, 0, stream>>>(dflag,
      d_in[20], d_in[21], d_in[22], d_in[23],
      d_in[24], d_in[25], d_in[26], d_in[27],
      d_in[28], d_in[29], d_in[30], d_in[31],
      LWf, lstm_bsum);

  count_kernel<<<(NEDGES + 255) / 256, 256, 0, stream>>>(dst, cnt);
  scan_kernel<<<1, 256, 0, stream>>>(cnt, row_ptr, cur);
  fill_kernel<<<(NEDGES + 255) / 256, 256, 0, stream>>>(dst, cur, eidx);
  uprep_kernel<<<(NEDGES + 255) / 256, 256, 0, stream>>>(
      dflag, edge_feats, We1, be1, eidx, uT);

  for (int step = 0; step < 6; ++step) {
    step_fused_kernel<<<NNODES / 64, 256, 0, stream>>>(
        We2T, be2T, uT, src, eidx, row_ptr, WxH, WhH, bxf, bhf, bconvf, hstate);
  }
  s2s6_kernel<<<NGRAPH / 2, 512, 0, stream>>>(dflag, hstate,
      (const float4*)LWf, lstm_bsum,
      Wout1, bout1, Wout2, bout2, (float*)d_out);
}